// Round 1
// 499.650 us; speedup vs baseline: 1.2955x; 1.2955x over previous
//
#include <hip/hip_runtime.h>

#define B_  4096
#define U_  256
#define N_  256
#define M_  64
#define BU  1048576   // B_*U_

// workspace layout (floats)
#define CV_OFF   0                         // 1024: LSTM constant vector (gate-major)
#define SM_OFF   1024                      // 512: softmax(A0) rows 0,1
#define MN_OFF   1536                      // 256: ||m0[n]||
#define RAW_OFF  2048                      // 4096*272: head params raw[b][0..267]
#define RAW_LD   272
#define YP_OFF   (RAW_OFF + 4096 * RAW_LD) // 4096*256: h @ W_ou[0:256] + b_ou

__device__ __forceinline__ float sigf(float x) { return 1.f / (1.f + expf(-x)); }
__device__ __forceinline__ float softplusf_(float x) { return (x > 15.f) ? x : log1pf(expf(x)); }

__device__ __forceinline__ float wave_sum(float v) {
  #pragma unroll
  for (int m = 32; m > 0; m >>= 1) v += __shfl_xor(v, m, 64);
  return v;
}
__device__ __forceinline__ float wave_max(float v) {
  #pragma unroll
  for (int m = 32; m > 0; m >>= 1) v = fmaxf(v, __shfl_xor(v, m, 64));
  return v;
}
// block(256)-wide reductions: wave shfl + 4-slot LDS combine (2 barriers each)
__device__ __forceinline__ float blk_sum(float v, float* red4, int t) {
  v = wave_sum(v);
  __syncthreads();
  if ((t & 63) == 0) red4[t >> 6] = v;
  __syncthreads();
  return red4[0] + red4[1] + red4[2] + red4[3];
}
__device__ __forceinline__ float blk_max(float v, float* red4, int t) {
  v = wave_max(v);
  __syncthreads();
  if ((t & 63) == 0) red4[t >> 6] = v;
  __syncthreads();
  return fmaxf(fmaxf(red4[0], red4[1]), fmaxf(red4[2], red4[3]));
}

// ============ K0: batch-invariant precompute ============
// blocks 0-3: cvec[1024] = b_lstm + rin@Wx[256:512] + h0@Wh  (rin = b_in + R0@W_in)
// block 4: softmax(A0) rows;  block 5: ||m0[n]||
__global__ __launch_bounds__(256) void ntm_k0_pre(
    const float* __restrict__ R0, const float* __restrict__ W_in, const float* __restrict__ b_in,
    const float* __restrict__ h0, const float* __restrict__ Wx, const float* __restrict__ Wh,
    const float* __restrict__ b_lstm, const float* __restrict__ A0, const float* __restrict__ m0,
    float* __restrict__ ws) {
  const int t = threadIdx.x, blk = blockIdx.x;
  __shared__ float rin[256];
  __shared__ float red4[4];
  if (blk < 4) {
    float a = b_in[t];
    #pragma unroll 8
    for (int i = 0; i < 64; ++i) a += R0[i] * W_in[i * 256 + t];
    rin[t] = a;
    __syncthreads();
    const int col = blk * 256 + t;
    float acc = b_lstm[col];
    #pragma unroll 4
    for (int j = 0; j < 256; ++j)
      acc += rin[j] * Wx[(size_t)(256 + j) * 1024 + col] + h0[j] * Wh[(size_t)j * 1024 + col];
    ws[CV_OFF + col] = acc;
  } else if (blk == 4) {
    for (int r = 0; r < 2; ++r) {
      float x = A0[r * 256 + t];
      float mx = blk_max(x, red4, t);
      float e = expf(x - mx);
      float s = blk_sum(e, red4, t);
      ws[SM_OFF + r * 256 + t] = e / s;
    }
  } else {
    const float4* mr = (const float4*)(m0 + (size_t)t * 64);
    float s = 0.f;
    #pragma unroll
    for (int q = 0; q < 16; ++q) { float4 v = mr[q]; s += v.x*v.x + v.y*v.y + v.z*v.z + v.w*v.w; }
    ws[MN_OFF + t] = sqrtf(s);
  }
}

// ============ K1: tiled gates GEMM (X @ Wx[0:256]) + LSTM ============
// grid 512 = 64 row-tiles x 8 u-tiles. Block: 64 rows x 32 u x 4 gates.
// Thread (tr,tc): rows tr*4..+3, u = {u0+tc*2, u0+tc*2+1}, all 4 gates.
__global__ __launch_bounds__(256) void ntm_k1_gates(
    const float* __restrict__ X, const float* __restrict__ Wx,
    const float* __restrict__ c0, const float* __restrict__ ws,
    float* __restrict__ out) {
  __shared__ float As[32][68];      // [k][row] transposed X tile (pad 68: b128-aligned, 2-way max)
  __shared__ float Bs[32][4][34];   // [k][gate][u_local] (conflict-free b64 reads)
  const int t = threadIdx.x;
  const int bm = blockIdx.x >> 3, bu = blockIdx.x & 7;
  const int b0 = bm << 6, u0 = bu << 5;
  const int tr = t >> 4, tc = t & 15;
  float accA[4][4] = {{0.f}};
  float accB[4][4] = {{0.f}};

  for (int kt = 0; kt < 256; kt += 32) {
    __syncthreads();
    { // stage X^T: coalesced 2xfloat4 global read, scalar LDS scatter
      const int row = t >> 2, kq = (t & 3) << 3;
      const float* p = X + (size_t)(b0 + row) * 256 + kt + kq;
      float4 v0 = *(const float4*)p, v1 = *(const float4*)(p + 4);
      As[kq+0][row]=v0.x; As[kq+1][row]=v0.y; As[kq+2][row]=v0.z; As[kq+3][row]=v0.w;
      As[kq+4][row]=v1.x; As[kq+5][row]=v1.y; As[kq+6][row]=v1.z; As[kq+7][row]=v1.w;
    }
    #pragma unroll
    for (int p = 0; p < 16; ++p) { // stage W: coalesced (u contiguous), conflict-free writes
      int idx = t + (p << 8);
      int ul = idx & 31, g = (idx >> 5) & 3, k = idx >> 7;
      Bs[k][g][ul] = Wx[(size_t)(kt + k) * 1024 + g * 256 + u0 + ul];
    }
    __syncthreads();
    #pragma unroll
    for (int k = 0; k < 32; ++k) {
      float4 av = *(const float4*)&As[k][tr << 2];
      float2 w0 = *(const float2*)&Bs[k][0][tc << 1];
      float2 w1 = *(const float2*)&Bs[k][1][tc << 1];
      float2 w2 = *(const float2*)&Bs[k][2][tc << 1];
      float2 w3 = *(const float2*)&Bs[k][3][tc << 1];
      float a_[4] = {av.x, av.y, av.z, av.w};
      #pragma unroll
      for (int i = 0; i < 4; ++i) {
        accA[i][0] += a_[i] * w0.x; accB[i][0] += a_[i] * w0.y;
        accA[i][1] += a_[i] * w1.x; accB[i][1] += a_[i] * w1.y;
        accA[i][2] += a_[i] * w2.x; accB[i][2] += a_[i] * w2.y;
        accA[i][3] += a_[i] * w3.x; accB[i][3] += a_[i] * w3.y;
      }
    }
  }
  const int ua = u0 + (tc << 1), ub = ua + 1;
  const float* cv = ws + CV_OFF;
  const float cva0 = cv[ua], cva1 = cv[256+ua], cva2 = cv[512+ua], cva3 = cv[768+ua];
  const float cvb0 = cv[ub], cvb1 = cv[256+ub], cvb2 = cv[512+ub], cvb3 = cv[768+ub];
  const float c0a = c0[ua], c0b = c0[ub];
  #pragma unroll
  for (int i = 0; i < 4; ++i) {
    const int b = b0 + (tr << 2) + i;
    {
      float ig = accA[i][0]+cva0, fg = accA[i][1]+cva1, gg = accA[i][2]+cva2, og = accA[i][3]+cva3;
      float ct = sigf(fg) * c0a + sigf(ig) * tanhf(gg);
      float h  = sigf(og) * tanhf(ct);
      out[BU + (size_t)b*256 + ua]     = h;
      out[2*BU + (size_t)b*256 + ua]   = ct;
    }
    {
      float ig = accB[i][0]+cvb0, fg = accB[i][1]+cvb1, gg = accB[i][2]+cvb2, og = accB[i][3]+cvb3;
      float ct = sigf(fg) * c0b + sigf(ig) * tanhf(gg);
      float h  = sigf(og) * tanhf(ct);
      out[BU + (size_t)b*256 + ub]     = h;
      out[2*BU + (size_t)b*256 + ub]   = ct;
    }
  }
}

// ============ K2: projection GEMM h @ [W_r | W_w | W_ou(0:256)] ============
// grid 576 = 64 row-tiles x 9 col-tiles (524 cols, last tile masked).
__global__ __launch_bounds__(256) void ntm_k2_proj(
    const float* __restrict__ hf,
    const float* __restrict__ W_r, const float* __restrict__ b_r,
    const float* __restrict__ W_w, const float* __restrict__ b_w,
    const float* __restrict__ W_ou, const float* __restrict__ b_ou,
    float* __restrict__ ws) {
  __shared__ float As[32][68];
  __shared__ float Bs[32][68];
  __shared__ const float* basep[64];
  __shared__ int stridep[64];
  __shared__ float biasp[64];
  const int t = threadIdx.x;
  const int bm = blockIdx.x & 63, bc = blockIdx.x >> 6;
  const int b0 = bm << 6, col0 = bc << 6;
  const int tr = t >> 4, tc = t & 15;
  if (t < 64) {
    int c = col0 + t;
    const float* bp; int st; float bi;
    if (c < 70)       { bp = W_r + c;          st = 70;  bi = b_r[c]; }
    else if (c < 268) { bp = W_w + (c - 70);   st = 198; bi = b_w[c - 70]; }
    else if (c < 524) { bp = W_ou + (c - 268); st = 256; bi = b_ou[c - 268]; }
    else              { bp = W_r; st = 0; bi = 0.f; }
    basep[t] = bp; stridep[t] = st; biasp[t] = bi;
  }
  float acc[4][4] = {{0.f}};
  for (int kt = 0; kt < 256; kt += 32) {
    __syncthreads();
    {
      const int row = t >> 2, kq = (t & 3) << 3;
      const float* p = hf + (size_t)(b0 + row) * 256 + kt + kq;
      float4 v0 = *(const float4*)p, v1 = *(const float4*)(p + 4);
      As[kq+0][row]=v0.x; As[kq+1][row]=v0.y; As[kq+2][row]=v0.z; As[kq+3][row]=v0.w;
      As[kq+4][row]=v1.x; As[kq+5][row]=v1.y; As[kq+6][row]=v1.z; As[kq+7][row]=v1.w;
    }
    #pragma unroll
    for (int p8 = 0; p8 < 8; ++p8) {
      int idx = t + (p8 << 8);
      int cl = idx & 63, k = idx >> 6;
      Bs[k][cl] = basep[cl][(size_t)(kt + k) * stridep[cl]];
    }
    __syncthreads();
    #pragma unroll
    for (int k = 0; k < 32; ++k) {
      float4 av = *(const float4*)&As[k][tr << 2];
      float4 wv = *(const float4*)&Bs[k][tc << 2];
      float a_[4] = {av.x, av.y, av.z, av.w};
      float w_[4] = {wv.x, wv.y, wv.z, wv.w};
      #pragma unroll
      for (int i = 0; i < 4; ++i)
        #pragma unroll
        for (int j = 0; j < 4; ++j)
          acc[i][j] += a_[i] * w_[j];
    }
  }
  #pragma unroll
  for (int j = 0; j < 4; ++j) {
    const int c = col0 + (tc << 2) + j;
    if (c >= 524) continue;
    const float bi = biasp[(tc << 2) + j];
    #pragma unroll
    for (int i = 0; i < 4; ++i) {
      const int b = b0 + (tr << 2) + i;
      const float v = acc[i][j] + bi;
      if (c < 268) ws[RAW_OFF + (size_t)b * RAW_LD + c] = v;
      else         ws[YP_OFF  + (size_t)b * 256 + (c - 268)] = v;
    }
  }
}

// ============ K3: addressing + read + y + memory write, one block per b ============
__global__ __launch_bounds__(256) void ntm_k3_addr(
    const float* __restrict__ m0, const float* __restrict__ W_ou,
    const float* __restrict__ ws, float* __restrict__ out) {
  __shared__ float rawS[272];
  __shared__ float kR[64], kW[64], erS[64], adS[64];
  __shared__ float wgR[256], wgW[256];
  __shared__ float wR[256], wW[256];
  __shared__ float red4[4];
  __shared__ float Rpart[4][64];
  __shared__ float Rv[64];
  const int t = threadIdx.x, b = blockIdx.x;

  rawS[t] = ws[RAW_OFF + (size_t)b * RAW_LD + t];
  if (t < 12) rawS[256 + t] = ws[RAW_OFF + (size_t)b * RAW_LD + 256 + t];
  __syncthreads();
  if (t < 64)       kR[t]        = tanhf(rawS[t]);
  else if (t < 128) kW[t - 64]   = tanhf(rawS[70 + (t - 64)]);
  else if (t < 192) erS[t - 128] = sigf(rawS[140 + (t - 128)]);
  else              adS[t - 192] = tanhf(rawS[204 + (t - 192)]);
  __syncthreads();

  const float betaR = softplusf_(rawS[64]),  gR = sigf(rawS[65]),  gammaR = softplusf_(rawS[69]);
  const float betaW = softplusf_(rawS[134]), gW = sigf(rawS[135]), gammaW = softplusf_(rawS[139]);
  float s0R, s1R, s2R, s0W, s1W, s2W;
  {
    float x0 = rawS[66], x1 = rawS[67], x2 = rawS[68];
    float m = fmaxf(x0, fmaxf(x1, x2));
    float e0 = expf(x0 - m), e1 = expf(x1 - m), e2 = expf(x2 - m);
    float inv = 1.f / (e0 + e1 + e2);
    s0R = e0 * inv; s1R = e1 * inv; s2R = e2 * inv;
  }
  {
    float x0 = rawS[136], x1 = rawS[137], x2 = rawS[138];
    float m = fmaxf(x0, fmaxf(x1, x2));
    float e0 = expf(x0 - m), e1 = expf(x1 - m), e2 = expf(x2 - m);
    float inv = 1.f / (e0 + e1 + e2);
    s0W = e0 * inv; s1W = e1 * inv; s2W = e2 * inv;
  }
  float sknR = 0.f, sknW = 0.f;
  const float4* kR4 = (const float4*)kR;
  const float4* kW4 = (const float4*)kW;
  #pragma unroll
  for (int q = 0; q < 16; ++q) {
    float4 a = kR4[q]; sknR += a.x*a.x + a.y*a.y + a.z*a.z + a.w*a.w;
    float4 c = kW4[q]; sknW += c.x*c.x + c.y*c.y + c.z*c.z + c.w*c.w;
  }
  const float knR = sqrtf(sknR), knW = sqrtf(sknW);

  const float apR = ws[SM_OFF + t], apW = ws[SM_OFF + 256 + t];
  const float mnv = ws[MN_OFF + t];

  float dR = 0.f, dW = 0.f;
  const float4* mrow = (const float4*)(m0 + (size_t)t * 64);
  #pragma unroll
  for (int q = 0; q < 16; ++q) {
    float4 mv = mrow[q]; float4 a = kR4[q]; float4 c = kW4[q];
    dR += mv.x*a.x + mv.y*a.y + mv.z*a.z + mv.w*a.w;
    dW += mv.x*c.x + mv.y*c.y + mv.z*c.z + mv.w*c.w;
  }
  const float xR = betaR * (dR / (knR * mnv + 1e-8f));
  const float xW = betaW * (dW / (knW * mnv + 1e-8f));

  float mxR = blk_max(xR, red4, t);
  float eR = expf(xR - mxR);
  float smR = blk_sum(eR, red4, t);
  float wcR = eR / smR;
  float mxW = blk_max(xW, red4, t);
  float eW = expf(xW - mxW);
  float smW = blk_sum(eW, red4, t);
  float wcW = eW / smW;

  wgR[t] = gR * wcR + (1.f - gR) * apR;
  wgW[t] = gW * wcW + (1.f - gW) * apW;
  __syncthreads();

  float cvR = s0R * wgR[t] + s1R * wgR[(t + 255) & 255] + s2R * wgR[(t + 1) & 255];
  float cvW = s0W * wgW[t] + s1W * wgW[(t + 255) & 255] + s2W * wgW[(t + 1) & 255];
  cvR = fmaxf(cvR, 0.f); cvW = fmaxf(cvW, 0.f);
  float shR = powf(cvR, gammaR);
  float shW = powf(cvW, gammaW);
  float ssR = fmaxf(blk_sum(shR, red4, t), 1e-37f);
  float ssW = fmaxf(blk_sum(shW, red4, t), 1e-37f);
  wR[t] = shR / ssR;
  wW[t] = shW / ssW;
  __syncthreads();

  { // R_t[m] = sum_n wR[n] * m0[n][m]
    int m = t & 63, ch = t >> 6;
    float p = 0.f;
    #pragma unroll 8
    for (int nn = ch * 64; nn < ch * 64 + 64; ++nn) p += wR[nn] * m0[(size_t)nn * 64 + m];
    Rpart[ch][m] = p;
  }
  __syncthreads();
  if (t < 64) Rv[t] = Rpart[0][t] + Rpart[1][t] + Rpart[2][t] + Rpart[3][t];
  __syncthreads();

  { // y = clip(ypart + R @ W_ou[256:320])
    float acc = ws[YP_OFF + (size_t)b * 256 + t];
    #pragma unroll 8
    for (int m = 0; m < 64; ++m) acc += Rv[m] * W_ou[(size_t)(256 + m) * 256 + t];
    acc = fminf(fmaxf(acc, -20.f), 20.f);
    out[(size_t)b * 256 + t] = acc;
  }

  { // m_t = m0*(1 - wW*erase) + wW*add
    const size_t mbase = (size_t)3 * BU + (size_t)b * 16384;
    #pragma unroll
    for (int i = 0; i < 8; ++i) {
      int basei = i * 2048 + t * 8;
      int nn = basei >> 6, mo = basei & 63;
      float4 v0 = *(const float4*)(m0 + basei);
      float4 v1 = *(const float4*)(m0 + basei + 4);
      float wv = wW[nn];
      float4 r0, r1;
      r0.x = v0.x * (1.f - wv * erS[mo + 0]) + wv * adS[mo + 0];
      r0.y = v0.y * (1.f - wv * erS[mo + 1]) + wv * adS[mo + 1];
      r0.z = v0.z * (1.f - wv * erS[mo + 2]) + wv * adS[mo + 2];
      r0.w = v0.w * (1.f - wv * erS[mo + 3]) + wv * adS[mo + 3];
      r1.x = v1.x * (1.f - wv * erS[mo + 4]) + wv * adS[mo + 4];
      r1.y = v1.y * (1.f - wv * erS[mo + 5]) + wv * adS[mo + 5];
      r1.z = v1.z * (1.f - wv * erS[mo + 6]) + wv * adS[mo + 6];
      r1.w = v1.w * (1.f - wv * erS[mo + 7]) + wv * adS[mo + 7];
      *(float4*)(out + mbase + basei)     = r0;
      *(float4*)(out + mbase + basei + 4) = r1;
    }
  }
}

extern "C" void kernel_launch(void* const* d_in, const int* in_sizes, int n_in,
                              void* d_out, int out_size, void* d_ws, size_t ws_size,
                              hipStream_t stream) {
  const float* X     = (const float*)d_in[0];
  const float* h0    = (const float*)d_in[1];
  const float* c0    = (const float*)d_in[2];
  const float* m0    = (const float*)d_in[3];
  const float* R0    = (const float*)d_in[4];
  const float* A0    = (const float*)d_in[5];
  const float* W_in  = (const float*)d_in[6];
  const float* b_in  = (const float*)d_in[7];
  const float* Wx    = (const float*)d_in[8];
  const float* Wh    = (const float*)d_in[9];
  const float* b_lstm= (const float*)d_in[10];
  const float* W_r   = (const float*)d_in[11];
  const float* b_r   = (const float*)d_in[12];
  const float* W_w   = (const float*)d_in[13];
  const float* b_w   = (const float*)d_in[14];
  const float* W_ou  = (const float*)d_in[15];
  const float* b_ou  = (const float*)d_in[16];
  float* out = (float*)d_out;
  float* ws  = (float*)d_ws;
  (void)ws_size; (void)in_sizes; (void)n_in; (void)out_size;

  ntm_k0_pre  <<<6,    256, 0, stream>>>(R0, W_in, b_in, h0, Wx, Wh, b_lstm, A0, m0, ws);
  ntm_k1_gates<<<512,  256, 0, stream>>>(X, Wx, c0, ws, out);
  ntm_k2_proj <<<576,  256, 0, stream>>>(out + BU, W_r, b_r, W_w, b_w, W_ou, b_ou, ws);
  ntm_k3_addr <<<4096, 256, 0, stream>>>(m0, W_ou, ws, out);
}